// Round 2
// baseline (126.982 us; speedup 1.0000x reference)
//
#include <hip/hip_runtime.h>
#include <math.h>

#define M_CHECKS 63
#define N_CODE   127
#define ROW_W    8
#define BATCH    4096
#define NITER    5
#define BIGF     1e10f

// One kernel. Each block: 4 waves = 4 batch rows. Per block we first rebuild
// the per-check column-index table (63 checks x 8 indices) from dense H via
// ballot+popcount (H is 32 KB, L2-resident; redundant per-block rebuild is
// cheaper than a second kernel launch). Then 5 flooding NMS iterations with
// the 127-float row state in LDS; lane i (<63) handles check i. Wave lockstep
// guarantees all gathers complete before any LDS atomic update issues.
__launch_bounds__(256, 4)
__global__ void nms_decode(const float* __restrict__ soft,
                           const int*   __restrict__ labels,
                           const int*   __restrict__ H,
                           const float* __restrict__ normalizor,
                           float*       __restrict__ out) {
    __shared__ float cur[4][128];
    __shared__ int   sidx[M_CHECKS * ROW_W];   // 504 ints

    const int tid  = threadIdx.x;
    const int w    = tid >> 6;
    const int lane = tid & 63;
    const int row  = blockIdx.x * 4 + w;

    // ---- build index table: wave w compacts check rows w, w+4, ... ----
    {
        const unsigned long long below =
            (lane == 0) ? 0ull : ((~0ull) >> (64 - lane));
        for (int i = w; i < M_CHECKS; i += 4) {
            const int c0 = lane;
            const int c1 = lane + 64;
            const int b0 = (H[i * N_CODE + c0] != 0) ? 1 : 0;
            const int b1 = (c1 < N_CODE) ? ((H[i * N_CODE + c1] != 0) ? 1 : 0) : 0;
            unsigned long long m0 = __ballot(b0);
            unsigned long long m1 = __ballot(b1);
            if (b0) {
                int pos = __popcll(m0 & below);
                if (pos < ROW_W) sidx[i * ROW_W + pos] = c0;
            }
            if (b1) {
                int pos = __popcll(m0) + __popcll(m1 & below);
                if (pos < ROW_W) sidx[i * ROW_W + pos] = c1;
            }
        }
    }

    const float norm = log1pf(expf(normalizor[0]));  // softplus(normalizor)

    // ---- load state + emit outs[0] and labels ----
    float* outLabels = out + (size_t)(NITER + 1) * BATCH * N_CODE;
    {
        const size_t base = (size_t)row * N_CODE;
        float v0 = soft[base + lane];
        cur[w][lane] = v0;
        out[base + lane] = v0;                                  // outs[0] = soft_input
        outLabels[base + lane] = (float)labels[base + lane];    // labels as 0.0/1.0
        if (lane < 63) {
            float v1 = soft[base + lane + 64];
            cur[w][lane + 64] = v1;
            out[base + lane + 64] = v1;
            outLabels[base + lane + 64] = (float)labels[base + lane + 64];
        }
    }
    __syncthreads();  // sidx ready; cur[w] is wave-private afterwards

    for (int it = 0; it < NITER; ++it) {
        float v[ROW_W];
        float s[ROW_W];
        int   c[ROW_W];
        float sprod = 1.0f, m1 = BIGF, m2 = BIGF;

        if (lane < M_CHECKS) {
            #pragma unroll
            for (int j = 0; j < ROW_W; ++j) {
                c[j] = sidx[lane * ROW_W + j];
                v[j] = cur[w][c[j]];
            }
            #pragma unroll
            for (int j = 0; j < ROW_W; ++j) {
                float x = v[j];
                s[j] = (x > 0.0f) ? 1.0f : ((x < 0.0f) ? -1.0f : 0.0f);
                sprod *= s[j];
                float av = fabsf(x);
                float proc = (av == 0.0f) ? BIGF : av;          // zeros/masked -> BIG
                if (proc < m1) { m2 = m1; m1 = proc; }
                else if (proc < m2) { m2 = proc; }
            }
            // wave lockstep: every lane's gather above completed before any
            // atomic below issues (single instruction stream per wave).
            #pragma unroll
            for (int j = 0; j < ROW_W; ++j) {
                float av  = fabsf(v[j]);
                float upd = (av == m1) ? m2 : m1;               // exact-equality rule
                float cv  = norm * upd * (sprod * s[j]);        // total_sign * sign_j
                atomicAdd(&cur[w][c[j]], cv);
            }
        }
        __threadfence_block();  // drain LDS atomics before re-reading cur[w]

        const size_t obase = (size_t)(it + 1) * BATCH * N_CODE + (size_t)row * N_CODE;
        out[obase + lane] = cur[w][lane];
        if (lane < 63) out[obase + lane + 64] = cur[w][lane + 64];
    }
}

extern "C" void kernel_launch(void* const* d_in, const int* in_sizes, int n_in,
                              void* d_out, int out_size, void* d_ws, size_t ws_size,
                              hipStream_t stream) {
    const float* soft       = (const float*)d_in[0];
    const int*   labels     = (const int*)d_in[1];
    const int*   H          = (const int*)d_in[2];
    const float* normalizor = (const float*)d_in[3];
    float*       out        = (float*)d_out;

    nms_decode<<<BATCH / 4, 256, 0, stream>>>(soft, labels, H, normalizor, out);
}

// Round 3
// 126.068 us; speedup vs baseline: 1.0073x; 1.0073x over previous
//
#include <hip/hip_runtime.h>
#include <math.h>

#define M_CHECKS 63
#define N_CODE   127
#define ROW_W    8
#define BATCH    4096
#define NITER    5
#define BIGF     1e10f

// One kernel. Each block: 4 waves = 4 batch rows. Per block we rebuild the
// per-check column-index table (63 checks x 8) from dense H via ballot+popcount
// (H is 32 KB, L1/L2-resident). Then 5 flooding NMS iterations with the
// 127-float row state in LDS; lane i (<63) handles check i. Wave lockstep
// guarantees all gathers complete before any LDS atomic update issues.
//
// KEY FIX vs round 2: the per-iteration fence is lgkmcnt(0) ONLY (wave-own
// LDS atomics), NOT __threadfence_block() — the latter emits
// s_waitcnt vmcnt(0) too, chaining every iteration on the previous
// iteration's 2 MB global store drain (the measured 89% stall).
__launch_bounds__(256, 4)
__global__ void nms_decode(const float* __restrict__ soft,
                           const int*   __restrict__ labels,
                           const int*   __restrict__ H,
                           const float* __restrict__ normalizor,
                           float*       __restrict__ out) {
    __shared__ float cur[4][128];
    __shared__ int   sidx[M_CHECKS * ROW_W];   // 504 ints

    const int tid  = threadIdx.x;
    const int w    = tid >> 6;
    const int lane = tid & 63;
    const int row  = blockIdx.x * 4 + w;

    // ---- build index table: wave w compacts check rows w, w+4, ... ----
    {
        const unsigned long long below =
            (lane == 0) ? 0ull : ((~0ull) >> (64 - lane));
        for (int i = w; i < M_CHECKS; i += 4) {
            const int c0 = lane;
            const int c1 = lane + 64;
            const int b0 = (H[i * N_CODE + c0] != 0) ? 1 : 0;
            const int b1 = (c1 < N_CODE) ? ((H[i * N_CODE + c1] != 0) ? 1 : 0) : 0;
            unsigned long long m0 = __ballot(b0);
            unsigned long long m1 = __ballot(b1);
            if (b0) {
                int pos = __popcll(m0 & below);
                if (pos < ROW_W) sidx[i * ROW_W + pos] = c0;
            }
            if (b1) {
                int pos = __popcll(m0) + __popcll(m1 & below);
                if (pos < ROW_W) sidx[i * ROW_W + pos] = c1;
            }
        }
    }

    const float norm = log1pf(expf(normalizor[0]));  // softplus(normalizor)

    // ---- load state + emit outs[0] and labels ----
    float* outLabels = out + (size_t)(NITER + 1) * BATCH * N_CODE;
    {
        const size_t base = (size_t)row * N_CODE;
        float v0 = soft[base + lane];
        cur[w][lane] = v0;
        out[base + lane] = v0;                                  // outs[0] = soft_input
        outLabels[base + lane] = (float)labels[base + lane];    // labels as 0.0/1.0
        if (lane < 63) {
            float v1 = soft[base + lane + 64];
            cur[w][lane + 64] = v1;
            out[base + lane + 64] = v1;
            outLabels[base + lane + 64] = (float)labels[base + lane + 64];
        }
    }
    __syncthreads();  // sidx ready; cur[w] is wave-private afterwards

    for (int it = 0; it < NITER; ++it) {
        float v[ROW_W];
        float s[ROW_W];
        int   c[ROW_W];
        float sprod = 1.0f, m1 = BIGF, m2 = BIGF;

        if (lane < M_CHECKS) {
            #pragma unroll
            for (int j = 0; j < ROW_W; ++j) {
                c[j] = sidx[lane * ROW_W + j];
                v[j] = cur[w][c[j]];
            }
            #pragma unroll
            for (int j = 0; j < ROW_W; ++j) {
                float x = v[j];
                s[j] = (x > 0.0f) ? 1.0f : ((x < 0.0f) ? -1.0f : 0.0f);
                sprod *= s[j];
                float av = fabsf(x);
                float proc = (av == 0.0f) ? BIGF : av;          // zeros/masked -> BIG
                if (proc < m1) { m2 = m1; m1 = proc; }
                else if (proc < m2) { m2 = proc; }
            }
            // wave lockstep: every lane's gather above completed before any
            // atomic below issues (single instruction stream per wave; DS ops
            // complete in order).
            #pragma unroll
            for (int j = 0; j < ROW_W; ++j) {
                float av  = fabsf(v[j]);
                float upd = (av == m1) ? m2 : m1;               // exact-equality rule
                float cv  = norm * upd * (sprod * s[j]);        // total_sign * sign_j
                atomicAdd(&cur[w][c[j]], cv);
            }
        }
        // Drain THIS WAVE's LDS atomics only. cur[w] is wave-private, so no
        // cross-wave sync is needed, and crucially no vmcnt(0): the global
        // output stores stay fire-and-forget.
        asm volatile("s_waitcnt lgkmcnt(0)" ::: "memory");
        __builtin_amdgcn_sched_barrier(0);

        const size_t obase = (size_t)(it + 1) * BATCH * N_CODE + (size_t)row * N_CODE;
        out[obase + lane] = cur[w][lane];
        if (lane < 63) out[obase + lane + 64] = cur[w][lane + 64];
    }
}

extern "C" void kernel_launch(void* const* d_in, const int* in_sizes, int n_in,
                              void* d_out, int out_size, void* d_ws, size_t ws_size,
                              hipStream_t stream) {
    const float* soft       = (const float*)d_in[0];
    const int*   labels     = (const int*)d_in[1];
    const int*   H          = (const int*)d_in[2];
    const float* normalizor = (const float*)d_in[3];
    float*       out        = (float*)d_out;

    nms_decode<<<BATCH / 4, 256, 0, stream>>>(soft, labels, H, normalizor, out);
}

// Round 4
// 97.915 us; speedup vs baseline: 1.2969x; 1.2875x over previous
//
#include <hip/hip_runtime.h>
#include <math.h>

#define M_CHECKS 63
#define N_CODE   127
#define ROW_W    8
#define BATCH    4096
#define NITER    5
#define BIGF     1e10f
#define MAXDEG   16

// Flooding NMS decoder, atomic-free.
// One wave = one batch row. Per iteration:
//   check phase : lane i (<63) gathers its 8 column values from LDS cur[],
//                 computes (min1, min2, sign_prod), publishes one float4.
//   column phase: each lane owns columns {lane, lane+64}; it re-derives its
//                 own contribution from the incident checks' summaries:
//                 x += norm * sign(x) * sum_i ((|x|==min1_i)? min2_i : min1_i) * sprod_i
// This replaces 8 LDS float atomicAdds (CAS-loop risk = round-2/3's 90% stall
// theory) with plain in-order ds_read/ds_write + two wave-own lgkmcnt(0).
__launch_bounds__(256, 4)
__global__ void nms_decode(const float* __restrict__ soft,
                           const int*   __restrict__ labels,
                           const int*   __restrict__ H,
                           const float* __restrict__ normalizor,
                           float*       __restrict__ out) {
    __shared__ float  cur[4][128];          // per-wave row state (gather source)
    __shared__ int    sidx[M_CHECKS * ROW_W];
    __shared__ float4 chk[4][64];           // per-wave check summaries (m1,m2,sprod,_)
    __shared__ int    csc[N_CODE * MAXDEG]; // column -> incident check ids
    __shared__ int    cnt[128];             // column degrees

    const int tid  = threadIdx.x;
    const int w    = tid >> 6;
    const int lane = tid & 63;
    const int row  = blockIdx.x * 4 + w;

    if (tid < 128) cnt[tid] = 0;

    // ---- build check->column table (ballot compaction of dense H) ----
    {
        const unsigned long long below =
            (lane == 0) ? 0ull : ((~0ull) >> (64 - lane));
        for (int i = w; i < M_CHECKS; i += 4) {
            const int c0 = lane;
            const int c1 = lane + 64;
            const int b0 = (H[i * N_CODE + c0] != 0) ? 1 : 0;
            const int b1 = (c1 < N_CODE) ? ((H[i * N_CODE + c1] != 0) ? 1 : 0) : 0;
            unsigned long long m0 = __ballot(b0);
            unsigned long long m1 = __ballot(b1);
            if (b0) {
                int pos = __popcll(m0 & below);
                if (pos < ROW_W) sidx[i * ROW_W + pos] = c0;
            }
            if (b1) {
                int pos = __popcll(m0) + __popcll(m1 & below);
                if (pos < ROW_W) sidx[i * ROW_W + pos] = c1;
            }
        }
    }
    __syncthreads();   // sidx + zeroed cnt visible

    // ---- build column->check table (wave 0; native int ds_add_rtn_u32) ----
    if (w == 0 && lane < M_CHECKS) {
        #pragma unroll
        for (int p = 0; p < ROW_W; ++p) {
            int c = sidx[lane * ROW_W + p];
            int slot = atomicAdd(&cnt[c], 1);
            if (slot < MAXDEG) csc[c * MAXDEG + slot] = lane;
        }
    }
    __syncthreads();   // csc + cnt visible to all waves

    const float norm = log1pf(expf(normalizor[0]));  // softplus
    float* outLabels = out + (size_t)(NITER + 1) * BATCH * N_CODE;

    const int j0 = lane;
    const int j1 = lane + 64;
    float x0, x1 = 0.0f;
    {
        const size_t base = (size_t)row * N_CODE;
        x0 = soft[base + j0];
        cur[w][j0] = x0;
        out[base + j0] = x0;                                   // outs[0]
        outLabels[base + j0] = (float)labels[base + j0];       // labels as 0.0/1.0
        if (lane < 63) {
            x1 = soft[base + j1];
            cur[w][j1] = x1;
            out[base + j1] = x1;
            outLabels[base + j1] = (float)labels[base + j1];
        }
    }
    const int deg0 = min(cnt[j0], MAXDEG);
    const int deg1 = (lane < 63) ? min(cnt[j1], MAXDEG) : 0;

    // cur writes are cross-lane within the wave: drain before first gather.
    asm volatile("s_waitcnt lgkmcnt(0)" ::: "memory");
    __builtin_amdgcn_sched_barrier(0);

    for (int it = 0; it < NITER; ++it) {
        // ---- check phase ----
        if (lane < M_CHECKS) {
            float m1 = BIGF, m2 = BIGF, sprod = 1.0f;
            #pragma unroll
            for (int p = 0; p < ROW_W; ++p) {
                int c   = sidx[lane * ROW_W + p];
                float x = cur[w][c];
                float s = (x > 0.0f) ? 1.0f : ((x < 0.0f) ? -1.0f : 0.0f);
                sprod *= s;
                float av   = fabsf(x);
                float proc = (av == 0.0f) ? BIGF : av;   // zeros -> BIG (ref rule)
                if (proc < m1) { m2 = m1; m1 = proc; }
                else if (proc < m2) { m2 = proc; }
            }
            chk[w][lane] = make_float4(m1, m2, sprod, 0.0f);
        }
        asm volatile("s_waitcnt lgkmcnt(0)" ::: "memory");   // summaries visible (wave-own)
        __builtin_amdgcn_sched_barrier(0);

        // ---- column phase (register-resident own values) ----
        {
            float av0 = fabsf(x0);
            float s0  = (x0 > 0.0f) ? 1.0f : ((x0 < 0.0f) ? -1.0f : 0.0f);
            float acc0 = 0.0f;
            for (int e = 0; e < deg0; ++e) {
                int i = csc[j0 * MAXDEG + e];
                float4 c4 = chk[w][i];
                float upd = (av0 == c4.x) ? c4.y : c4.x;  // exact-equality rule
                acc0 += upd * c4.z;
            }
            x0 += norm * s0 * acc0;

            float av1 = fabsf(x1);
            float s1  = (x1 > 0.0f) ? 1.0f : ((x1 < 0.0f) ? -1.0f : 0.0f);
            float acc1 = 0.0f;
            for (int e = 0; e < deg1; ++e) {
                int i = csc[j1 * MAXDEG + e];
                float4 c4 = chk[w][i];
                float upd = (av1 == c4.x) ? c4.y : c4.x;
                acc1 += upd * c4.z;
            }
            x1 += norm * s1 * acc1;
        }

        cur[w][j0] = x0;
        if (lane < 63) cur[w][j1] = x1;

        const size_t obase = (size_t)(it + 1) * BATCH * N_CODE + (size_t)row * N_CODE;
        out[obase + j0] = x0;
        if (lane < 63) out[obase + j1] = x1;

        // new cur visible to next iteration's gathers (wave-own DS only;
        // global stores stay fire-and-forget)
        asm volatile("s_waitcnt lgkmcnt(0)" ::: "memory");
        __builtin_amdgcn_sched_barrier(0);
    }
}

extern "C" void kernel_launch(void* const* d_in, const int* in_sizes, int n_in,
                              void* d_out, int out_size, void* d_ws, size_t ws_size,
                              hipStream_t stream) {
    const float* soft       = (const float*)d_in[0];
    const int*   labels     = (const int*)d_in[1];
    const int*   H          = (const int*)d_in[2];
    const float* normalizor = (const float*)d_in[3];
    float*       out        = (float*)d_out;

    nms_decode<<<BATCH / 4, 256, 0, stream>>>(soft, labels, H, normalizor, out);
}

// Round 6
// 80.273 us; speedup vs baseline: 1.5819x; 1.2198x over previous
//
#include <hip/hip_runtime.h>
#include <math.h>

#define M_CHECKS 63
#define N_CODE   127
#define ROW_W    8
#define BATCH    4096
#define NITER    5
#define BIGF     1e10f
#define MAXD     16   // max column degree; proven sufficient (rounds 3-4 passed with clamp@16)

// Flooding NMS decoder, atomic-free and (column-phase) bank-conflict-free.
// One wave = one batch row.
//   check phase : lane i (<63) gathers its 8 column values from LDS cur[],
//                 computes (min1,min2,sign_prod) and writes the FINISHED
//                 per-edge contribution cv = norm*upd*sprod*s directly to
//                 cvals[slot][col] (slot-major layout).
//   column phase: lane owns cols {lane, lane+64}; sums a fixed, unrolled
//                 16-slot strip cvals[e*128+j] — bank = j%32, 2 lanes/bank
//                 => conflict-free — then updates x in registers.
// Unused slots are zeroed once and never written, so the fixed-length sum
// needs no degree bookkeeping. All per-edge index tables are hoisted to
// registers before the loop (the stride-8/16 conflict reads happen once).
__launch_bounds__(256, 4)
__global__ void nms_decode(const float* __restrict__ soft,
                           const int*   __restrict__ labels,
                           const int*   __restrict__ H,
                           const float* __restrict__ normalizor,
                           float*       __restrict__ out) {
    __shared__ float cur[4][128];             // per-wave row state
    __shared__ float cvals[4][MAXD][128];     // per-wave slot-major edge contributions (32 KB)
    __shared__ int   sidx[M_CHECKS * ROW_W];  // check -> column
    __shared__ int   sslot[M_CHECKS * ROW_W]; // check -> slot within column
    __shared__ int   cnt[128];                // column degrees (build only)

    const int tid  = threadIdx.x;
    const int w    = tid >> 6;
    const int lane = tid & 63;
    const int row  = blockIdx.x * 4 + w;

    // zero cvals (padding slots must read as 0.0 forever) + cnt
    {
        float4* cv4 = (float4*)cvals;
        #pragma unroll
        for (int t = 0; t < (4 * MAXD * 128) / 4 / 256; ++t)
            cv4[tid + t * 256] = make_float4(0.f, 0.f, 0.f, 0.f);
        if (tid < 128) cnt[tid] = 0;
    }

    // ---- build check->column table (ballot compaction of dense H) ----
    {
        const unsigned long long below =
            (lane == 0) ? 0ull : ((~0ull) >> (64 - lane));
        for (int i = w; i < M_CHECKS; i += 4) {
            const int c0 = lane;
            const int c1 = lane + 64;
            const int b0 = (H[i * N_CODE + c0] != 0) ? 1 : 0;
            const int b1 = (c1 < N_CODE) ? ((H[i * N_CODE + c1] != 0) ? 1 : 0) : 0;
            unsigned long long m0 = __ballot(b0);
            unsigned long long m1 = __ballot(b1);
            if (b0) {
                int pos = __popcll(m0 & below);
                if (pos < ROW_W) sidx[i * ROW_W + pos] = c0;
            }
            if (b1) {
                int pos = __popcll(m0) + __popcll(m1 & below);
                if (pos < ROW_W) sidx[i * ROW_W + pos] = c1;
            }
        }
    }
    __syncthreads();   // sidx + zeroed cnt/cvals visible

    // ---- assign per-edge slots (wave 0; native integer LDS atomics) ----
    if (w == 0 && lane < M_CHECKS) {
        #pragma unroll
        for (int p = 0; p < ROW_W; ++p) {
            int c = sidx[lane * ROW_W + p];
            sslot[lane * ROW_W + p] = atomicAdd(&cnt[c], 1);   // < MAXD, proven
        }
    }
    __syncthreads();   // sslot visible to all waves

    const float norm = log1pf(expf(normalizor[0]));  // softplus
    float* outLabels = out + (size_t)(NITER + 1) * BATCH * N_CODE;
    float* const cvw = &cvals[w][0][0];

    // ---- hoist per-check edge tables into registers (conflicts paid once) ----
    int ec[ROW_W];     // column of edge p
    int widx[ROW_W];   // slot*128 + column  (cvals write offset)
    if (lane < M_CHECKS) {
        #pragma unroll
        for (int p = 0; p < ROW_W; ++p) {
            ec[p]   = sidx[lane * ROW_W + p];
            widx[p] = sslot[lane * ROW_W + p] * 128 + ec[p];
        }
    }

    // ---- load state + emit outs[0] and labels ----
    const int j0 = lane;
    const int j1 = lane + 64;           // lane 63 -> 127: pad column, never stored
    float x0, x1 = 0.0f;
    {
        const size_t base = (size_t)row * N_CODE;
        x0 = soft[base + j0];
        cur[w][j0] = x0;
        out[base + j0] = x0;                                   // outs[0]
        outLabels[base + j0] = (float)labels[base + j0];       // labels as 0.0/1.0
        if (lane < 63) {
            x1 = soft[base + j1];
            cur[w][j1] = x1;
            out[base + j1] = x1;
            outLabels[base + j1] = (float)labels[base + j1];
        }
    }
    // cur writes are cross-lane within the wave: drain before first gather.
    asm volatile("s_waitcnt lgkmcnt(0)" ::: "memory");
    __builtin_amdgcn_sched_barrier(0);

    for (int it = 0; it < NITER; ++it) {
        // ---- check phase ----
        if (lane < M_CHECKS) {
            float v[ROW_W];
            #pragma unroll
            for (int p = 0; p < ROW_W; ++p) v[p] = cur[w][ec[p]];

            float m1 = BIGF, m2 = BIGF, sprod = 1.0f;
            #pragma unroll
            for (int p = 0; p < ROW_W; ++p) {
                float x = v[p];
                float s = (x > 0.0f) ? 1.0f : ((x < 0.0f) ? -1.0f : 0.0f);
                sprod *= s;
                float av   = fabsf(x);
                float proc = (av == 0.0f) ? BIGF : av;          // zeros -> BIG (ref rule)
                if (proc < m1) { m2 = m1; m1 = proc; }
                else if (proc < m2) { m2 = proc; }
            }
            const float nsp = norm * sprod;
            #pragma unroll
            for (int p = 0; p < ROW_W; ++p) {
                float x   = v[p];
                float s   = (x > 0.0f) ? 1.0f : ((x < 0.0f) ? -1.0f : 0.0f);
                float av  = fabsf(x);
                float upd = (av == m1) ? m2 : m1;               // exact-equality rule
                cvw[widx[p]] = nsp * upd * s;                   // finished contribution
            }
        }
        asm volatile("s_waitcnt lgkmcnt(0)" ::: "memory");      // wave-own DS drain
        __builtin_amdgcn_sched_barrier(0);

        // ---- column phase: fixed-length, conflict-free strip sums ----
        float acc0 = 0.0f, acc1 = 0.0f;
        #pragma unroll
        for (int e = 0; e < MAXD; ++e) acc0 += cvw[e * 128 + j0];
        #pragma unroll
        for (int e = 0; e < MAXD; ++e) acc1 += cvw[e * 128 + j1];
        x0 += acc0;
        x1 += acc1;

        cur[w][j0] = x0;
        if (lane < 63) cur[w][j1] = x1;

        const size_t obase = (size_t)(it + 1) * BATCH * N_CODE + (size_t)row * N_CODE;
        out[obase + j0] = x0;
        if (lane < 63) out[obase + j1] = x1;

        // new cur visible to next iteration's gathers (wave-own DS only)
        asm volatile("s_waitcnt lgkmcnt(0)" ::: "memory");
        __builtin_amdgcn_sched_barrier(0);
    }
}

extern "C" void kernel_launch(void* const* d_in, const int* in_sizes, int n_in,
                              void* d_out, int out_size, void* d_ws, size_t ws_size,
                              hipStream_t stream) {
    const float* soft       = (const float*)d_in[0];
    const int*   labels     = (const int*)d_in[1];
    const int*   H          = (const int*)d_in[2];
    const float* normalizor = (const float*)d_in[3];
    float*       out        = (float*)d_out;

    nms_decode<<<BATCH / 4, 256, 0, stream>>>(soft, labels, H, normalizor, out);
}